// Round 12
// baseline (679.233 us; speedup 1.0000x reference)
//
#include <hip/hip_runtime.h>
#include <float.h>

// SearchTransfer MI355X — R12: hi-only f16 GEMM (no split terms). K'=192
// (144 hi + pad), 3 chunks of 64 k', 256² tile (R10 structure — R11 showed
// 2-blocks/CU DMA rate scales sub-linearly, so minimize bytes at max tile).
// Guard: tau = 1.0*bns (worst-case C-S bound = 1.0*bns; Hoeffding P(escape)
// ~ e^-96 per pair) + pruned exact fp32 fixup (unchanged). Traffic 850->510MB.
// B=2, C=16, H=W=96, k=3,pad=1,stride=1, lv=2. L=9216, KF=144.
// out = [T_org (2*16*192*192 f32), S (2*9216 as f32)]

#define BATCH 2
#define CCH   16
#define HH    96
#define WW    96
#define LP    9216
#define KF    144
#define K3    192      // 3 chunks x 64 k'; granules 0-17 data (hi), 18-23 pad
#define OH    192
#define OW    192
#define NRT2  36       // row tiles of 256
#define NCB2  36       // col blocks of 256

typedef _Float16 f16;
typedef __attribute__((ext_vector_type(8))) _Float16 f16x8;
typedef __attribute__((ext_vector_type(4))) float    f32x4;

__device__ __forceinline__ void async16(const void* g, void* l) {
    __builtin_amdgcn_global_load_lds(
        (const __attribute__((address_space(1))) void*)g,
        (__attribute__((address_space(3))) void*)l, 16, 0, 0);
}

// ---------------------------------------------------- fused norm + pack ----
// Block = (py, batch, side*4+quarter). Norms bit-identical (zero-padded terms
// exact). 24 rows x 24 granules; granule g: f = g*8+e, hi-f16 only.
// side 0: A = f16(a*1024*rinv) (rinv written). side 1: B = f16(b*1024) (bns).
__global__ __launch_bounds__(256) void k_pack2(
        const float* __restrict__ ref, const float* __restrict__ lr,
        float* __restrict__ rinv, float* __restrict__ bns,
        f16* __restrict__ Abig, f16* __restrict__ Bbig) {
    __shared__ float imgS[CCH][3][26];   // x origin at global xi = q*24-1
    __shared__ float scl[24];
    int py = blockIdx.x, b = blockIdx.y;
    int side = blockIdx.z >> 2, q = blockIdx.z & 3;
    int tid = threadIdx.x;
    const float* img = (side ? lr : ref) + (size_t)b * CCH * HH * WW;

    for (int i = tid; i < CCH * 3 * 26; i += 256) {
        int c = i / 78, rem = i - c * 78;
        int rr = rem / 26, xx = rem - rr * 26;
        int y = py + rr - 1, xi = q * 24 - 1 + xx;
        float v = 0.f;
        if ((unsigned)y < (unsigned)HH && (unsigned)xi < (unsigned)WW)
            v = img[(c * HH + y) * WW + xi];
        imgS[c][rr][xx] = v;
    }
    __syncthreads();

    if (tid < 24) {
        int pxl = tid;
        float s = 0.f;
        for (int c = 0; c < CCH; ++c)
            #pragma unroll
            for (int dy = 0; dy < 3; ++dy)
                #pragma unroll
                for (int dx = 0; dx < 3; ++dx) {
                    float v = imgS[c][dy][pxl + dx];   // 0 when OOB: exact
                    s += v * v;
                }
        int gl = b * LP + py * 96 + q * 24 + pxl;
        if (side) { bns[gl] = 1024.0f * sqrtf(s); scl[pxl] = 1024.0f; }
        else { float r = 1.0f / fmaxf(sqrtf(s), 1e-12f); rinv[gl] = r; scl[pxl] = 1024.0f * r; }
    }
    __syncthreads();

    f16* dstb = (side ? Bbig : Abig) + (size_t)(b * LP + py * 96 + q * 24) * K3;
    for (int i = tid; i < 24 * 24; i += 256) {          // 24 granules/row
        int pxl = i / 24, g = i - pxl * 24;
        float sc = scl[pxl];
        f16x8 o;
        if (g >= 18) { f16x8 z = {0,0,0,0,0,0,0,0}; o = z; }
        else {
            #pragma unroll
            for (int e = 0; e < 8; ++e) {
                int f = g * 8 + e;                      // 0..143
                int c = f / 9, r9 = f - c * 9;
                int dy = r9 / 3, dx = r9 - dy * 3;
                float v = imgS[c][dy][pxl + dx] * sc;
                o[e] = (f16)v;
            }
        }
        *(f16x8*)(dstb + (size_t)pxl * K3 + g * 8) = o;
    }
}

// -------------------------------------------------- MFMA GEMM + top-2 ------
// 256x256 block, 16 waves (4x4 of 64x64 micro-tiles), 3 chunks of 64 k',
// double-buffered LDS (128 KB), post-barrier prefetch, XCD swizzle. Plain
// hi*hi f16 MFMA (2 ks steps x 16 MFMA per chunk).
__global__ __launch_bounds__(1024) void k_mfma(
        const f16* __restrict__ Abig, const f16* __restrict__ Bbig,
        float* __restrict__ pv1, int* __restrict__ pi1, float* __restrict__ pv2) {
    __shared__ f16 smem[2][512 * 64];                  // 128 KB; rows 0-255=A, 256-511=B
    int tid = threadIdx.x, lane = tid & 63, w = tid >> 6;   // w: 0..15
    int wm = w & 3, wn = w >> 2;
    int l15 = lane & 15, quad = lane >> 4, l7 = lane & 7;

    int i = blockIdx.x;                // 0..2591
    int xcd = i & 7, slot = i >> 3;    // slot 0..323
    int cb = slot / 9;                 // col tile 0..35 (major)
    int brt = xcd * 9 + (slot - cb * 9);   // 0..71
    int b = brt / NRT2, rt = brt - b * NRT2;
    int r0 = rt * 256, c0 = cb * 256;

    // staging: 64 groups of 8 rows; wave w owns groups w*4..w*4+3.
    int srow = lane >> 3;              // row within group
    int sg   = (lane & 7) ^ srow;      // source granule (self-inverse swizzle)
    const f16* gsrc[4];
    int ldsbyte[4];                    // wave-uniform byte offset in one buffer
    #pragma unroll
    for (int j = 0; j < 4; ++j) {
        int G = w * 4 + j;             // 0..63
        int row8 = G * 8 + srow;       // 0..511 (A rows then B rows)
        const f16* base = (row8 < 256)
            ? Abig + (size_t)(b * LP + r0 + row8) * K3
            : Bbig + (size_t)(b * LP + c0 + (row8 - 256)) * K3;
        gsrc[j] = base + sg * 8;
        ldsbyte[j] = G * 1024;         // G*8 rows * 128 B/row
    }
    int arow[4], brow[4];              // frag row byte offsets (row stride 128 B)
    #pragma unroll
    for (int t = 0; t < 4; ++t) {
        arow[t] = (wm * 64 + t * 16 + l15) * 128;
        brow[t] = (256 + wn * 64 + t * 16 + l15) * 128;
    }

    f32x4 acc[4][4];
    #pragma unroll
    for (int ii = 0; ii < 4; ++ii)
        #pragma unroll
        for (int j = 0; j < 4; ++j) { acc[ii][j][0]=0.f; acc[ii][j][1]=0.f; acc[ii][j][2]=0.f; acc[ii][j][3]=0.f; }

    // prologue: chunk 0 -> buf 0
    #pragma unroll
    for (int j = 0; j < 4; ++j) async16(gsrc[j], (char*)smem[0] + ldsbyte[j]);

    for (int ch = 0; ch < 3; ++ch) {
        __syncthreads();               // drains own DMA; buf[ch&1] ready
        if (ch < 2) {
            #pragma unroll
            for (int j = 0; j < 4; ++j)
                async16(gsrc[j] + (ch + 1) * 64, (char*)smem[(ch + 1) & 1] + ldsbyte[j]);
        }
        const char* buf = (const char*)smem[ch & 1];
        #pragma unroll
        for (int ks = 0; ks < 2; ++ks) {
            int ph = (((ks << 2) + quad) ^ l7) << 4;
            f16x8 af[4], bf[4];
            #pragma unroll
            for (int t = 0; t < 4; ++t) af[t] = *(const f16x8*)(buf + arow[t] + ph);
            #pragma unroll
            for (int t = 0; t < 4; ++t) bf[t] = *(const f16x8*)(buf + brow[t] + ph);
            #pragma unroll
            for (int rtt = 0; rtt < 4; ++rtt)
                #pragma unroll
                for (int ct = 0; ct < 4; ++ct)
                    acc[rtt][ct] = __builtin_amdgcn_mfma_f32_16x16x32_f16(af[rtt], bf[ct], acc[rtt][ct], 0, 0, 0);
        }
    }
    __syncthreads();                   // smem reads done -> overlay epilogue scratch

    float* sv1 = (float*)smem;                         // [4][256]
    int*   si1 = (int*)  ((char*)smem + 4096);
    float* sv2 = (float*)((char*)smem + 8192);

    int rbase = r0 + wm * 64 + (quad << 2);
    #pragma unroll
    for (int ct = 0; ct < 4; ++ct) {
        float v1 = -FLT_MAX, v2 = -FLT_MAX; int i1 = 0;
        #pragma unroll
        for (int rtt = 0; rtt < 4; ++rtt)
            #pragma unroll
            for (int e = 0; e < 4; ++e) {              // ascending rows; strict > = first wins
                float v = acc[rtt][ct][e];
                int rg = rbase + rtt * 16 + e;
                if (v > v1) { v2 = v1; v1 = v; i1 = rg; }
                else if (v > v2) v2 = v;
            }
        #pragma unroll
        for (int off = 16; off < 64; off <<= 1) {      // reduce over quad (rows)
            float ov1 = __shfl_xor(v1, off, 64);
            int   oi1 = __shfl_xor(i1, off, 64);
            float ov2 = __shfl_xor(v2, off, 64);
            if (ov1 > v1 || (ov1 == v1 && oi1 < i1)) { v2 = fmaxf(v1, ov2); v1 = ov1; i1 = oi1; }
            else v2 = fmaxf(v2, ov1);
        }
        if (quad == 0) {
            int col = wn * 64 + ct * 16 + l15;
            sv1[wm * 256 + col] = v1; si1[wm * 256 + col] = i1; sv2[wm * 256 + col] = v2;
        }
    }
    __syncthreads();
    if (tid < 256) {
        int col = tid;
        float v1 = sv1[col]; int i1 = si1[col]; float v2 = sv2[col];
        #pragma unroll
        for (int m = 1; m < 4; ++m) {                  // ascending wm = ascending rows
            float ov1 = sv1[m * 256 + col]; int oi1 = si1[m * 256 + col]; float ov2 = sv2[m * 256 + col];
            if (ov1 > v1) { v2 = fmaxf(v1, ov2); v1 = ov1; i1 = oi1; }
            else v2 = fmaxf(v2, ov1);
        }
        size_t o = ((size_t)(b * NRT2 + rt)) * LP + c0 + col;
        pv1[o] = v1; pi1[o] = i1; pv2[o] = v2;
    }
}

// -------------------------------------- fused merge + fixup + fold ---------
// Block = (b, 16x16 pixel tile). Phase A: merge <=10x10 patch neighborhood
// over 36 row-chunks (ascending rc = first-wins; flag iff gap < tau =
// 1.0*bns — worst-case hi-only f16 error bound); owner patches write Sout.
// Phase B: pruned exact fp32 argmax for flagged patches (idempotent across
// neighbor blocks). Phase C: fold with S from LDS, reused across 16 channels.
__global__ __launch_bounds__(256) void k_foldmerge(
        const float* __restrict__ refimg, const float* __restrict__ lrimg,
        const float* __restrict__ rinv,
        const float* __restrict__ pv1, const int* __restrict__ pi1,
        const float* __restrict__ pv2, const float* __restrict__ bns,
        const float* __restrict__ org,
        float* __restrict__ outT, float* __restrict__ Sout) {
    __shared__ int   s_S[10][10];
    __shared__ int   s_flag[100];
    __shared__ int   s_nflag;
    __shared__ float bcol[KF];
    __shared__ float spv[NRT2];
    __shared__ float red[4]; __shared__ int redi[4];
    int tx = blockIdx.x, ty = blockIdx.y, b = blockIdx.z;
    int x0 = tx * 16, y0 = ty * 16;
    int lhb = 8 * ty - 1; if (lhb < 0) lhb = 0;
    int lwb = 8 * tx - 1; if (lwb < 0) lwb = 0;
    int lhe = 8 * ty + 8; if (lhe > 95) lhe = 95;
    int lwe = 8 * tx + 8; if (lwe > 95) lwe = 95;
    int tid = threadIdx.x;

    if (tid == 0) s_nflag = 0;
    __syncthreads();

    // ---- Phase A: merge ----
    if (tid < 100) {
        int ph = tid / 10, pw = tid - ph * 10;
        int lh = lhb + ph, lw = lwb + pw;
        if (lh <= lhe && lw <= lwe) {
            int col = lh * 96 + lw;
            float v1 = -FLT_MAX, v2 = -FLT_MAX; int i1 = 0;
            for (int rc = 0; rc < NRT2; ++rc) {        // ascending: first-wins
                size_t o = ((size_t)(b * NRT2 + rc)) * LP + col;
                float cv1 = pv1[o]; int ci1 = pi1[o]; float cv2 = pv2[o];
                if (cv1 > v1) { v2 = fmaxf(v1, cv2); v1 = cv1; i1 = ci1; }
                else v2 = fmaxf(v2, cv1);
            }
            s_S[ph][pw] = i1;
            float tau = bns[b * LP + col];             // 1.0 * bns
            if (v1 - v2 < tau) { int k = atomicAdd(&s_nflag, 1); s_flag[k] = tid; }
            if (lh >= 8 * ty && lh < 8 * ty + 8 && lw >= 8 * tx && lw < 8 * tx + 8)
                Sout[b * LP + col] = (float)i1;        // owner write (partition)
        }
    }
    __syncthreads();

    // ---- Phase B: exact fixup for flagged patches ----
    int nf = s_nflag;
    for (int fi = 0; fi < nf; ++fi) {
        int pt = s_flag[fi];
        int ph = pt / 10, pw = pt - ph * 10;
        int lh = lhb + ph, lw = lwb + pw;
        int col = lh * 96 + lw, gid = b * LP + col;
        __syncthreads();                               // protect bcol/spv reuse
        if (tid < KF) {
            int c = tid / 9, r = tid - c * 9;
            int dy = r / 3, dx = r - dy * 3;
            int y = lh + dy - 1, x = lw + dx - 1;
            float v = 0.f;
            if ((unsigned)y < (unsigned)HH && (unsigned)x < (unsigned)WW)
                v = lrimg[((size_t)(b * CCH + c) * HH + y) * WW + x];
            bcol[tid] = v;
        }
        if (tid < NRT2) spv[tid] = pv1[((size_t)(b * NRT2 + tid)) * LP + col];
        __syncthreads();
        float v1 = -FLT_MAX;
        for (int rc = 0; rc < NRT2; ++rc) v1 = fmaxf(v1, spv[rc]);
        float thresh = v1 - bns[gid];                  // v1 - tau
        float best = -FLT_MAX; int bi = 0x7fffffff;
        for (int rc = 0; rc < NRT2; ++rc) {            // ascending rows
            if (spv[rc] < thresh) continue;            // prune (uniform)
            int row = rc * 256 + tid;
            int py = row / WW, px = row - py * WW;
            float s = 0.f;
            for (int c = 0; c < CCH; ++c) {
                const float* ic = refimg + (size_t)(b * CCH + c) * HH * WW;
                #pragma unroll
                for (int dy = 0; dy < 3; ++dy) {
                    int y = py + dy - 1;
                    if ((unsigned)y >= (unsigned)HH) continue;
                    #pragma unroll
                    for (int dx = 0; dx < 3; ++dx) {
                        int x = px + dx - 1;
                        if ((unsigned)x >= (unsigned)WW) continue;
                        s = fmaf(ic[y * WW + x], bcol[c * 9 + dy * 3 + dx], s);
                    }
                }
            }
            s *= rinv[b * LP + row];
            if (s > best || (s == best && row < bi)) { best = s; bi = row; }
        }
        #pragma unroll
        for (int off = 1; off < 64; off <<= 1) {
            float ov = __shfl_xor(best, off, 64);
            int   oi = __shfl_xor(bi, off, 64);
            if (ov > best || (ov == best && oi < bi)) { best = ov; bi = oi; }
        }
        if ((tid & 63) == 0) { red[tid >> 6] = best; redi[tid >> 6] = bi; }
        __syncthreads();
        if (tid == 0) {
            float b0 = red[0]; int i0 = redi[0];
            for (int k = 1; k < 4; ++k)
                if (red[k] > b0 || (red[k] == b0 && redi[k] < i0)) { b0 = red[k]; i0 = redi[k]; }
            s_S[ph][pw] = i0;
            if (lh >= 8 * ty && lh < 8 * ty + 8 && lw >= 8 * tx && lw < 8 * tx + 8)
                Sout[gid] = (float)i0;
        }
    }
    __syncthreads();

    // ---- Phase C: fold (per pixel, all 16 channels) ----
    int pyL = tid >> 4, pxL = tid & 15;
    int y = y0 + pyL, x = x0 + pxL;
    const float* orgb = org + (size_t)b * CCH * OH * OW;
    float acc[CCH];
    #pragma unroll
    for (int c = 0; c < CCH; ++c) acc[c] = 0.f;
    int lhm = (y + 2) >> 1;
    int lwm = (x + 2) >> 1;
    int lh0 = lhm - 2 > 0 ? lhm - 2 : 0;
    int lh1 = lhm < 95 ? lhm : 95;
    int lw0 = lwm - 2 > 0 ? lwm - 2 : 0;
    int lw1 = lwm < 95 ? lwm : 95;
    for (int lh = lh0; lh <= lh1; ++lh) {
        int dy = y + 2 - 2 * lh;
        if (dy > 5) continue;
        for (int lw = lw0; lw <= lw1; ++lw) {
            int dx = x + 2 - 2 * lw;
            if (dx > 5) continue;
            int s  = s_S[lh - lhb][lw - lwb];
            int sh = s / 96, sw = s - sh * 96;
            int u = 2 * sh + dy - 2;
            int v = 2 * sw + dx - 2;
            if ((unsigned)u < (unsigned)OH && (unsigned)v < (unsigned)OW) {
                const float* p = orgb + u * OW + v;
                #pragma unroll
                for (int c = 0; c < CCH; ++c) acc[c] += p[(size_t)c * OH * OW];
            }
        }
    }
    #pragma unroll
    for (int c = 0; c < CCH; ++c)
        outT[(((size_t)(b * CCH + c)) * OH + y) * OW + x] = acc[c];
}

// --------------------------------------------------------------- launch ----
extern "C" void kernel_launch(void* const* d_in, const int* in_sizes, int n_in,
                              void* d_out, int out_size, void* d_ws, size_t ws_size,
                              hipStream_t stream) {
    const float* lrsr  = (const float*)d_in[0];
    const float* refsr = (const float*)d_in[1];
    const float* org   = (const float*)d_in[2];

    char* ws = (char*)d_ws;
    size_t o = 0;
    float* rinv     = (float*)(ws + o); o += (size_t)BATCH * LP * 4;
    float* bns      = (float*)(ws + o); o += (size_t)BATCH * LP * 4;
    float* pv1      = (float*)(ws + o); o += (size_t)BATCH * NRT2 * LP * 4;
    int*   pi1      = (int*)  (ws + o); o += (size_t)BATCH * NRT2 * LP * 4;
    float* pv2      = (float*)(ws + o); o += (size_t)BATCH * NRT2 * LP * 4;
    f16*   Abig     = (f16*)  (ws + o); o += (size_t)BATCH * LP * K3 * 2;
    f16*   Bbig     = (f16*)  (ws + o); o += (size_t)BATCH * LP * K3 * 2;

    float* outT = (float*)d_out;                          // 2*16*192*192
    float* outS = outT + (size_t)BATCH * CCH * OH * OW;   // 2*9216 as f32

    k_pack2<<<dim3(96, BATCH, 8), 256, 0, stream>>>(refsr, lrsr, rinv, bns, Abig, Bbig);
    k_mfma<<<dim3(NCB2 * NRT2 * BATCH), 1024, 0, stream>>>(Abig, Bbig, pv1, pi1, pv2);
    k_foldmerge<<<dim3(12, 12, BATCH), 256, 0, stream>>>(refsr, lrsr, rinv, pv1, pi1, pv2, bns,
                                                         org, outT, outS);
}